// Round 1
// baseline (5470.523 us; speedup 1.0000x reference)
//
#include <hip/hip_runtime.h>

#define NC   50000
#define NE   500000
#define DIN  313
#define DNE  580
#define HIDD 256

// ---------------- child encoder: x = relu(cf @ Wc + bc) * exists ----------------
// M=50000 (16 nodes/block), K=313 (chunks of 32), N=256. 256 threads, 4x4 reg tile.
__global__ __launch_bounds__(256) void child_kernel(
    const float* __restrict__ cf, const float* __restrict__ exists,
    const float* __restrict__ W, const float* __restrict__ bias,
    float* __restrict__ x)
{
    __shared__ float sA[16][36];       // +pad, 144B row stride (16B aligned)
    __shared__ float sB[32][256];
    const int tid = threadIdx.x;
    const int node0 = blockIdx.x * 16;
    const int tr = tid >> 6;           // 0..3
    const int tc = tid & 63;           // 0..63
    float acc[4][4] = {};

    for (int ch = 0; ch < 10; ++ch) {  // ceil(313/32)
        const int kbase = ch * 32;
        // stage A: 16x32 elems, 2 per thread
        #pragma unroll
        for (int i = 0; i < 2; ++i) {
            int flat = tid + i * 256;
            int me = flat >> 5, kk = flat & 31;
            int gk = kbase + kk;
            sA[me][kk] = (gk < DIN) ? cf[(size_t)(node0 + me) * DIN + gk] : 0.0f;
        }
        // stage B: 32x256 floats as float4, 8 per thread
        #pragma unroll
        for (int i = 0; i < 8; ++i) {
            int f4 = tid + i * 256;          // 0..2047
            int kr = f4 >> 6, c4 = f4 & 63;
            int gk = kbase + kr;
            float4 v = make_float4(0.f, 0.f, 0.f, 0.f);
            if (gk < DIN) v = *(const float4*)(W + (size_t)gk * 256 + c4 * 4);
            *(float4*)(&sB[kr][c4 * 4]) = v;
        }
        __syncthreads();
        #pragma unroll
        for (int kq = 0; kq < 8; ++kq) {
            float4 w0 = *(const float4*)&sB[kq * 4 + 0][tc * 4];
            float4 w1 = *(const float4*)&sB[kq * 4 + 1][tc * 4];
            float4 w2 = *(const float4*)&sB[kq * 4 + 2][tc * 4];
            float wj[4][4] = {{w0.x,w0.y,w0.z,w0.w},{w1.x,w1.y,w1.z,w1.w},
                              {w2.x,w2.y,w2.z,w2.w},{0,0,0,0}};
            float4 w3 = *(const float4*)&sB[kq * 4 + 3][tc * 4];
            wj[3][0]=w3.x; wj[3][1]=w3.y; wj[3][2]=w3.z; wj[3][3]=w3.w;
            #pragma unroll
            for (int r = 0; r < 4; ++r) {
                float4 a = *(const float4*)&sA[tr * 4 + r][kq * 4];
                float av[4] = {a.x, a.y, a.z, a.w};
                #pragma unroll
                for (int j = 0; j < 4; ++j)
                    #pragma unroll
                    for (int c = 0; c < 4; ++c)
                        acc[r][c] = fmaf(av[j], wj[j][c], acc[r][c]);
            }
        }
        __syncthreads();
    }
    float4 bb = *(const float4*)&bias[tc * 4];
    float bv[4] = {bb.x, bb.y, bb.z, bb.w};
    #pragma unroll
    for (int r = 0; r < 4; ++r) {
        int node = node0 + tr * 4 + r;
        float ex = exists[node];
        float4 o;
        o.x = fmaxf(acc[r][0] + bv[0], 0.f) * ex;
        o.y = fmaxf(acc[r][1] + bv[1], 0.f) * ex;
        o.z = fmaxf(acc[r][2] + bv[2], 0.f) * ex;
        o.w = fmaxf(acc[r][3] + bv[3], 0.f) * ex;
        *(float4*)(x + (size_t)node * 256 + tc * 4) = o;
    }
}

// ---------------- fused edge layer: scatter_add(relu([x[s],x[d],ef] @ W + b)) ----------------
// 32 edges/block, K=580 in chunks of 32 (19 chunks), 256 threads, 8x4 reg tile.
__global__ __launch_bounds__(256) void edge_kernel(
    const float* __restrict__ x, const float* __restrict__ eto,
    const float* __restrict__ efe, const int* __restrict__ eidx,
    const float* __restrict__ W, const float* __restrict__ bias,
    float* __restrict__ accb)
{
    __shared__ float sA[32][36];
    __shared__ float sB[32][256];
    __shared__ int s_src[32], s_dst[32];

    const int tid = threadIdx.x;
    const int e0 = blockIdx.x * 32;     // NE % 32 == 0, no tail
    if (tid < 32) {
        s_src[tid] = eidx[2 * (e0 + tid)];
        s_dst[tid] = eidx[2 * (e0 + tid) + 1];
    }
    const int tr = tid >> 6;            // 0..3
    const int tc = tid & 63;            // 0..63
    const int ame = tid >> 3;           // stage-A row 0..31
    const int akq = (tid & 7) * 4;      // stage-A k offset 0..28
    float acc[8][4] = {};
    __syncthreads();

    for (int ch = 0; ch < 19; ++ch) {   // ceil(580/32)
        const int kbase = ch * 32;
        // stage A (gathered nef chunk): 32 edges x 32 k, one float4 per thread
        {
            int gk = kbase + akq;
            float4 v;
            if (ch < 8) {
                v = *(const float4*)(x + (size_t)s_src[ame] * 256 + gk);
            } else if (ch < 16) {
                v = *(const float4*)(x + (size_t)s_dst[ame] * 256 + (gk - 256));
            } else {
                int e = e0 + ame;
                float tmpv[4];
                #pragma unroll
                for (int j = 0; j < 4; ++j) {
                    int g = gk + j;
                    float t = 0.f;
                    if (g < DNE) {
                        int rel = g - 512;
                        t = (rel < 4) ? eto[(size_t)e * 4 + rel]
                                      : efe[(size_t)e * 64 + (rel - 4)];
                    }
                    tmpv[j] = t;
                }
                v = make_float4(tmpv[0], tmpv[1], tmpv[2], tmpv[3]);
            }
            *(float4*)(&sA[ame][akq]) = v;
        }
        // stage B: 32x256 W chunk
        #pragma unroll
        for (int i = 0; i < 8; ++i) {
            int f4 = tid + i * 256;
            int kr = f4 >> 6, c4 = f4 & 63;
            int gk = kbase + kr;
            float4 v = make_float4(0.f, 0.f, 0.f, 0.f);
            if (gk < DNE) v = *(const float4*)(W + (size_t)gk * 256 + c4 * 4);
            *(float4*)(&sB[kr][c4 * 4]) = v;
        }
        __syncthreads();
        #pragma unroll
        for (int kq = 0; kq < 8; ++kq) {
            float4 w0 = *(const float4*)&sB[kq * 4 + 0][tc * 4];
            float4 w1 = *(const float4*)&sB[kq * 4 + 1][tc * 4];
            float4 w2 = *(const float4*)&sB[kq * 4 + 2][tc * 4];
            float4 w3 = *(const float4*)&sB[kq * 4 + 3][tc * 4];
            float wj[4][4] = {{w0.x,w0.y,w0.z,w0.w},{w1.x,w1.y,w1.z,w1.w},
                              {w2.x,w2.y,w2.z,w2.w},{w3.x,w3.y,w3.z,w3.w}};
            #pragma unroll
            for (int r = 0; r < 8; ++r) {
                float4 a = *(const float4*)&sA[tr * 8 + r][kq * 4];
                float av[4] = {a.x, a.y, a.z, a.w};
                #pragma unroll
                for (int j = 0; j < 4; ++j)
                    #pragma unroll
                    for (int c = 0; c < 4; ++c)
                        acc[r][c] = fmaf(av[j], wj[j][c], acc[r][c]);
            }
        }
        __syncthreads();
    }
    float4 bb = *(const float4*)&bias[tc * 4];
    float bv[4] = {bb.x, bb.y, bb.z, bb.w};
    #pragma unroll
    for (int r = 0; r < 8; ++r) {
        int node = s_src[tr * 8 + r];
        float* dst = accb + (size_t)node * 256 + tc * 4;
        #pragma unroll
        for (int c = 0; c < 4; ++c) {
            float v = fmaxf(acc[r][c] + bv[c], 0.f);
            atomicAdd(&dst[c], v);
        }
    }
}

// ---------------- per-node scale + column max ----------------
__global__ __launch_bounds__(256) void finalize_kernel(
    const float* __restrict__ src, const float* __restrict__ inv,
    float* __restrict__ x_out, float* __restrict__ pmax, int n)
{
    const int tid = threadIdx.x;
    int i0 = blockIdx.x * 128;
    int iend = i0 + 128; if (iend > n) iend = n;
    float m = 0.0f;
    for (int i = i0; i < iend; ++i) {
        float v = src[(size_t)i * 256 + tid];
        if (inv)   v *= inv[i];
        if (x_out) x_out[(size_t)i * 256 + tid] = v;
        m = fmaxf(m, v);
    }
    // all values >= 0 (relu / mean of relu) -> uint compare == float compare
    atomicMax((unsigned int*)&pmax[tid], __float_as_uint(m));
}

__global__ __launch_bounds__(256) void count_kernel(
    const int* __restrict__ eidx, float* __restrict__ cnt, int E)
{
    int t = blockIdx.x * 256 + threadIdx.x;
    if (t < E) atomicAdd(&cnt[eidx[2 * t]], 1.0f);
}

__global__ __launch_bounds__(256) void inv_kernel(float* __restrict__ cnt, int n)
{
    int t = blockIdx.x * 256 + threadIdx.x;
    if (t < n) cnt[t] = 1.0f / fmaxf(cnt[t], 1.0f);
}

__global__ __launch_bounds__(256) void parent_kernel(
    const float* __restrict__ pmax, const float* __restrict__ W,
    const float* __restrict__ bias, float* __restrict__ out)
{
    __shared__ float sp[768];
    const int tid = threadIdx.x;
    for (int i = tid; i < 768; i += 256) sp[i] = pmax[i];
    __syncthreads();
    float s = bias[tid];
    for (int k = 0; k < 768; ++k) s = fmaf(sp[k], W[(size_t)k * 256 + tid], s);
    out[tid] = fmaxf(s, 0.f);
}

extern "C" void kernel_launch(void* const* d_in, const int* in_sizes, int n_in,
                              void* d_out, int out_size, void* d_ws, size_t ws_size,
                              hipStream_t stream)
{
    const float* cf   = (const float*)d_in[0];
    const float* ex   = (const float*)d_in[1];
    const float* eto  = (const float*)d_in[2];
    const float* efe  = (const float*)d_in[3];
    const int*   eidx = (const int*)d_in[4];
    const float* Wc   = (const float*)d_in[5];
    const float* bc   = (const float*)d_in[6];
    const float* W0   = (const float*)d_in[7];
    const float* b0   = (const float*)d_in[8];
    const float* W1   = (const float*)d_in[9];
    const float* b1   = (const float*)d_in[10];
    const float* Wp   = (const float*)d_in[11];
    const float* bp   = (const float*)d_in[12];

    float* x    = (float*)d_ws;                      // 50000*256
    float* accb = x + (size_t)NC * 256;              // 50000*256
    float* cnt  = accb + (size_t)NC * 256;           // 50000
    float* pmax = cnt + NC;                          // 3*256

    hipMemsetAsync(pmax, 0, 768 * sizeof(float), stream);
    hipMemsetAsync(cnt, 0, NC * sizeof(float), stream);

    child_kernel<<<NC / 16, 256, 0, stream>>>(cf, ex, Wc, bc, x);
    count_kernel<<<(NE + 255) / 256, 256, 0, stream>>>(eidx, cnt, NE);
    inv_kernel<<<(NC + 255) / 256, 256, 0, stream>>>(cnt, NC);
    finalize_kernel<<<(NC + 127) / 128, 256, 0, stream>>>(x, nullptr, nullptr, pmax, NC);

    for (int it = 0; it < 2; ++it) {
        const float* W = it ? W1 : W0;
        const float* b = it ? b1 : b0;
        hipMemsetAsync(accb, 0, (size_t)NC * 256 * sizeof(float), stream);
        edge_kernel<<<NE / 32, 256, 0, stream>>>(x, eto, efe, eidx, W, b, accb);
        finalize_kernel<<<(NC + 127) / 128, 256, 0, stream>>>(accb, cnt, x, pmax + 256 * (it + 1), NC);
    }
    parent_kernel<<<1, 256, 0, stream>>>(pmax, Wp, bp, (float*)d_out);
}

// Round 2
// 1335.102 us; speedup vs baseline: 4.0975x; 4.0975x over previous
//
#include <hip/hip_runtime.h>

#define NC   50000
#define NE   500000
#define DIN  313
#define DNE  580
#define KP   608          // padded K for edge GEMM (19*32)

typedef __attribute__((ext_vector_type(8))) short bf16x8;
typedef __attribute__((ext_vector_type(4))) float f32x4;

static __device__ __forceinline__ unsigned short f2bf(float f) {
    unsigned u = __float_as_uint(f);
    unsigned r = (u + 0x7fff + ((u >> 16) & 1)) >> 16;   // RNE
    return (unsigned short)r;
}

// ---------------- child encoder: xf = relu(cf @ Wc + bc) * exists (fp32) ----------------
__global__ __launch_bounds__(256) void child_kernel(
    const float* __restrict__ cf, const float* __restrict__ exists,
    const float* __restrict__ W, const float* __restrict__ bias,
    float* __restrict__ x)
{
    __shared__ float sA[16][36];
    __shared__ float sB[32][256];
    const int tid = threadIdx.x;
    const int node0 = blockIdx.x * 16;
    const int tr = tid >> 6;
    const int tc = tid & 63;
    float acc[4][4] = {};

    for (int ch = 0; ch < 10; ++ch) {
        const int kbase = ch * 32;
        #pragma unroll
        for (int i = 0; i < 2; ++i) {
            int flat = tid + i * 256;
            int me = flat >> 5, kk = flat & 31;
            int gk = kbase + kk;
            sA[me][kk] = (gk < DIN) ? cf[(size_t)(node0 + me) * DIN + gk] : 0.0f;
        }
        #pragma unroll
        for (int i = 0; i < 8; ++i) {
            int f4 = tid + i * 256;
            int kr = f4 >> 6, c4 = f4 & 63;
            int gk = kbase + kr;
            float4 v = make_float4(0.f, 0.f, 0.f, 0.f);
            if (gk < DIN) v = *(const float4*)(W + (size_t)gk * 256 + c4 * 4);
            *(float4*)(&sB[kr][c4 * 4]) = v;
        }
        __syncthreads();
        #pragma unroll
        for (int kq = 0; kq < 8; ++kq) {
            float4 w0 = *(const float4*)&sB[kq * 4 + 0][tc * 4];
            float4 w1 = *(const float4*)&sB[kq * 4 + 1][tc * 4];
            float4 w2 = *(const float4*)&sB[kq * 4 + 2][tc * 4];
            float4 w3 = *(const float4*)&sB[kq * 4 + 3][tc * 4];
            float wj[4][4] = {{w0.x,w0.y,w0.z,w0.w},{w1.x,w1.y,w1.z,w1.w},
                              {w2.x,w2.y,w2.z,w2.w},{w3.x,w3.y,w3.z,w3.w}};
            #pragma unroll
            for (int r = 0; r < 4; ++r) {
                float4 a = *(const float4*)&sA[tr * 4 + r][kq * 4];
                float av[4] = {a.x, a.y, a.z, a.w};
                #pragma unroll
                for (int j = 0; j < 4; ++j)
                    #pragma unroll
                    for (int c = 0; c < 4; ++c)
                        acc[r][c] = fmaf(av[j], wj[j][c], acc[r][c]);
            }
        }
        __syncthreads();
    }
    float4 bb = *(const float4*)&bias[tc * 4];
    float bv[4] = {bb.x, bb.y, bb.z, bb.w};
    #pragma unroll
    for (int r = 0; r < 4; ++r) {
        int node = node0 + tr * 4 + r;
        float ex = exists[node];
        float4 o;
        o.x = fmaxf(acc[r][0] + bv[0], 0.f) * ex;
        o.y = fmaxf(acc[r][1] + bv[1], 0.f) * ex;
        o.z = fmaxf(acc[r][2] + bv[2], 0.f) * ex;
        o.w = fmaxf(acc[r][3] + bv[3], 0.f) * ex;
        *(float4*)(x + (size_t)node * 256 + tc * 4) = o;
    }
}

// ---------------- W -> transposed padded bf16: Wt[layer][n][k], k in [0,608) ----------------
__global__ __launch_bounds__(256) void prep_w_kernel(
    const float* __restrict__ W0, const float* __restrict__ W1,
    unsigned short* __restrict__ Wtb)
{
    int b = blockIdx.x;             // 0..511
    int layer = b >> 8, n = b & 255;
    const float* W = layer ? W1 : W0;
    unsigned short* dst = Wtb + (size_t)layer * 256 * KP + (size_t)n * KP;
    for (int k = threadIdx.x; k < KP; k += 256) {
        float v = (k < DNE) ? W[(size_t)k * 256 + n] : 0.0f;
        dst[k] = f2bf(v);
    }
}

// ---------------- fused edge layer (bf16 MFMA): accb += relu([x[s],x[d],ef] @ W + b) ----------------
// 64 edges/block, 4 waves (2 M x 2 N), wave tile 32x128, K chunks of 32 (19).
__global__ __launch_bounds__(256) void edge_mfma_kernel(
    const unsigned short* __restrict__ xb,
    const float* __restrict__ eto, const float* __restrict__ efe,
    const int* __restrict__ eidx,
    const unsigned short* __restrict__ Wtb,   // [256][KP]
    const float* __restrict__ bias,
    float* __restrict__ accb)
{
    __shared__ unsigned short sA[64][40];     // 80 B row stride -> 2-way aliasing only
    __shared__ unsigned short sB[256][40];
    __shared__ int s_src[64], s_dst[64];

    const int tid = threadIdx.x;
    const int e0 = blockIdx.x * 64;
    if (tid < 64) {
        int e = e0 + tid; if (e >= NE) e = NE - 1;
        s_src[tid] = eidx[2 * e];
        s_dst[tid] = eidx[2 * e + 1];
    }
    const int lane = tid & 63;
    const int wid  = tid >> 6;
    const int wm   = wid >> 1;     // 0..1 -> M half
    const int wn   = wid & 1;      // 0..1 -> N half
    const int l15  = lane & 15;
    const int l4   = lane >> 4;

    const int arow = tid >> 2;            // 0..63 (staging)
    const int acol = (tid & 3) * 8;       // 0,8,16,24

    f32x4 acc[2][8];
    #pragma unroll
    for (int mi = 0; mi < 2; ++mi)
        #pragma unroll
        for (int ni = 0; ni < 8; ++ni)
            acc[mi][ni] = (f32x4){0.f, 0.f, 0.f, 0.f};

    __syncthreads();

    for (int ch = 0; ch < 19; ++ch) {
        const int k0 = ch * 32;
        // ---- stage A: 64 edges x 32 k (gathered) ----
        if (ch < 8) {
            int4 v = *(const int4*)(xb + (size_t)s_src[arow] * 256 + k0 + acol);
            *(int4*)&sA[arow][acol] = v;
        } else if (ch < 16) {
            int4 v = *(const int4*)(xb + (size_t)s_dst[arow] * 256 + (k0 - 256) + acol);
            *(int4*)&sA[arow][acol] = v;
        } else {
            int e = e0 + arow; if (e >= NE) e = NE - 1;
            int gk = k0 + acol - 512;      // ef-local col 0..95
            union { unsigned short u[8]; int4 v; } pk;
            #pragma unroll
            for (int j = 0; j < 8; ++j) {
                int g = gk + j;
                float f = 0.0f;
                if (g < 4)       f = eto[(size_t)e * 4 + g];
                else if (g < 68) f = efe[(size_t)e * 64 + (g - 4)];
                pk.u[j] = f2bf(f);
            }
            *(int4*)&sA[arow][acol] = pk.v;
        }
        // ---- stage B: 256 n x 32 k from Wt ----
        #pragma unroll
        for (int i = 0; i < 4; ++i) {
            int s = tid + i * 256;
            int n = s >> 2, c8 = (s & 3) * 8;
            int4 v = *(const int4*)(Wtb + (size_t)n * KP + k0 + c8);
            *(int4*)&sB[n][c8] = v;
        }
        __syncthreads();
        // ---- MFMA ----
        bf16x8 af[2];
        #pragma unroll
        for (int mi = 0; mi < 2; ++mi)
            af[mi] = *(const bf16x8*)&sA[wm * 32 + mi * 16 + l15][l4 * 8];
        #pragma unroll
        for (int ni = 0; ni < 8; ++ni) {
            bf16x8 bfr = *(const bf16x8*)&sB[wn * 128 + ni * 16 + l15][l4 * 8];
            acc[0][ni] = __builtin_amdgcn_mfma_f32_16x16x32_bf16(af[0], bfr, acc[0][ni], 0, 0, 0);
            acc[1][ni] = __builtin_amdgcn_mfma_f32_16x16x32_bf16(af[1], bfr, acc[1][ni], 0, 0, 0);
        }
        __syncthreads();
    }

    // ---- epilogue: relu(acc + bias) scatter-add by src ----
    float bv[8];
    #pragma unroll
    for (int ni = 0; ni < 8; ++ni)
        bv[ni] = bias[wn * 128 + ni * 16 + l15];

    #pragma unroll
    for (int mi = 0; mi < 2; ++mi) {
        #pragma unroll
        for (int r = 0; r < 4; ++r) {
            int erow = wm * 32 + mi * 16 + l4 * 4 + r;
            if (e0 + erow < NE) {
                float* dst = accb + (size_t)s_src[erow] * 256;
                #pragma unroll
                for (int ni = 0; ni < 8; ++ni) {
                    float v = fmaxf(acc[mi][ni][r] + bv[ni], 0.f);
                    atomicAdd(&dst[wn * 128 + ni * 16 + l15], v);
                }
            }
        }
    }
}

// ---------------- per-node scale + bf16 convert + column max ----------------
__global__ __launch_bounds__(256) void finalize_kernel(
    const float* __restrict__ src, const float* __restrict__ inv,
    unsigned short* __restrict__ xb_out, float* __restrict__ pmax, int n)
{
    const int tid = threadIdx.x;
    int i0 = blockIdx.x * 128;
    int iend = i0 + 128; if (iend > n) iend = n;
    float m = 0.0f;
    for (int i = i0; i < iend; ++i) {
        float v = src[(size_t)i * 256 + tid];
        if (inv) v *= inv[i];
        xb_out[(size_t)i * 256 + tid] = f2bf(v);
        m = fmaxf(m, v);
    }
    atomicMax((unsigned int*)&pmax[tid], __float_as_uint(m));  // all v >= 0
}

__global__ __launch_bounds__(256) void count_kernel(
    const int* __restrict__ eidx, float* __restrict__ cnt, int E)
{
    int t = blockIdx.x * 256 + threadIdx.x;
    if (t < E) atomicAdd(&cnt[eidx[2 * t]], 1.0f);
}

__global__ __launch_bounds__(256) void inv_kernel(float* __restrict__ cnt, int n)
{
    int t = blockIdx.x * 256 + threadIdx.x;
    if (t < n) cnt[t] = 1.0f / fmaxf(cnt[t], 1.0f);
}

__global__ __launch_bounds__(256) void parent_kernel(
    const float* __restrict__ pmax, const float* __restrict__ W,
    const float* __restrict__ bias, float* __restrict__ out)
{
    __shared__ float sp[768];
    const int tid = threadIdx.x;
    for (int i = tid; i < 768; i += 256) sp[i] = pmax[i];
    __syncthreads();
    float s = bias[tid];
    for (int k = 0; k < 768; ++k) s = fmaf(sp[k], W[(size_t)k * 256 + tid], s);
    out[tid] = fmaxf(s, 0.f);
}

extern "C" void kernel_launch(void* const* d_in, const int* in_sizes, int n_in,
                              void* d_out, int out_size, void* d_ws, size_t ws_size,
                              hipStream_t stream)
{
    const float* cf   = (const float*)d_in[0];
    const float* ex   = (const float*)d_in[1];
    const float* eto  = (const float*)d_in[2];
    const float* efe  = (const float*)d_in[3];
    const int*   eidx = (const int*)d_in[4];
    const float* Wc   = (const float*)d_in[5];
    const float* bc   = (const float*)d_in[6];
    const float* W0   = (const float*)d_in[7];
    const float* b0   = (const float*)d_in[8];
    const float* W1   = (const float*)d_in[9];
    const float* b1   = (const float*)d_in[10];
    const float* Wp   = (const float*)d_in[11];
    const float* bp   = (const float*)d_in[12];

    // workspace layout
    float*          accb = (float*)d_ws;                         // 50000*256 f32 (also child tmp)
    float*          cnt  = accb + (size_t)NC * 256;              // 50000 f32
    float*          pmax = cnt + NC;                             // 768 f32
    unsigned short* xb   = (unsigned short*)(pmax + 768);        // 50000*256 bf16
    unsigned short* Wtb  = xb + (size_t)NC * 256;                // 2*256*608 bf16

    hipMemsetAsync(pmax, 0, 768 * sizeof(float), stream);
    hipMemsetAsync(cnt, 0, NC * sizeof(float), stream);

    prep_w_kernel<<<512, 256, 0, stream>>>(W0, W1, Wtb);
    child_kernel<<<NC / 16, 256, 0, stream>>>(cf, ex, Wc, bc, accb);
    count_kernel<<<(NE + 255) / 256, 256, 0, stream>>>(eidx, cnt, NE);
    inv_kernel<<<(NC + 255) / 256, 256, 0, stream>>>(cnt, NC);
    finalize_kernel<<<(NC + 127) / 128, 256, 0, stream>>>(accb, nullptr, xb, pmax, NC);

    for (int it = 0; it < 2; ++it) {
        const unsigned short* Wt = Wtb + (size_t)it * 256 * KP;
        const float* b = it ? b1 : b0;
        hipMemsetAsync(accb, 0, (size_t)NC * 256 * sizeof(float), stream);
        edge_mfma_kernel<<<(NE + 63) / 64, 256, 0, stream>>>(xb, eto, efe, eidx, Wt, b, accb);
        finalize_kernel<<<(NC + 127) / 128, 256, 0, stream>>>(accb, cnt, xb, pmax + 256 * (it + 1), NC);
    }
    parent_kernel<<<1, 256, 0, stream>>>(pmax, Wp, bp, (float*)d_out);
}

// Round 3
// 1180.504 us; speedup vs baseline: 4.6341x; 1.1310x over previous
//
#include <hip/hip_runtime.h>

#define NC   50000
#define NE   500000
#define DIN  313
#define DNE  580
#define KP   608          // padded K for edge GEMM (19*32)
#define NB_SCAN 196       // ceil(NC/256)

typedef __attribute__((ext_vector_type(8))) short bf16x8;
typedef __attribute__((ext_vector_type(4))) float f32x4;

static __device__ __forceinline__ unsigned short f2bf(float f) {
    unsigned u = __float_as_uint(f);
    unsigned r = (u + 0x7fff + ((u >> 16) & 1)) >> 16;   // RNE
    return (unsigned short)r;
}

// ---------------- child encoder: xf = relu(cf @ Wc + bc) * exists (fp32) ----------------
__global__ __launch_bounds__(256) void child_kernel(
    const float* __restrict__ cf, const float* __restrict__ exists,
    const float* __restrict__ W, const float* __restrict__ bias,
    float* __restrict__ x)
{
    __shared__ float sA[16][36];
    __shared__ float sB[32][256];
    const int tid = threadIdx.x;
    const int node0 = blockIdx.x * 16;
    const int tr = tid >> 6;
    const int tc = tid & 63;
    float acc[4][4] = {};

    for (int ch = 0; ch < 10; ++ch) {
        const int kbase = ch * 32;
        #pragma unroll
        for (int i = 0; i < 2; ++i) {
            int flat = tid + i * 256;
            int me = flat >> 5, kk = flat & 31;
            int gk = kbase + kk;
            sA[me][kk] = (gk < DIN) ? cf[(size_t)(node0 + me) * DIN + gk] : 0.0f;
        }
        #pragma unroll
        for (int i = 0; i < 8; ++i) {
            int f4 = tid + i * 256;
            int kr = f4 >> 6, c4 = f4 & 63;
            int gk = kbase + kr;
            float4 v = make_float4(0.f, 0.f, 0.f, 0.f);
            if (gk < DIN) v = *(const float4*)(W + (size_t)gk * 256 + c4 * 4);
            *(float4*)(&sB[kr][c4 * 4]) = v;
        }
        __syncthreads();
        #pragma unroll
        for (int kq = 0; kq < 8; ++kq) {
            float4 w0 = *(const float4*)&sB[kq * 4 + 0][tc * 4];
            float4 w1 = *(const float4*)&sB[kq * 4 + 1][tc * 4];
            float4 w2 = *(const float4*)&sB[kq * 4 + 2][tc * 4];
            float4 w3 = *(const float4*)&sB[kq * 4 + 3][tc * 4];
            float wj[4][4] = {{w0.x,w0.y,w0.z,w0.w},{w1.x,w1.y,w1.z,w1.w},
                              {w2.x,w2.y,w2.z,w2.w},{w3.x,w3.y,w3.z,w3.w}};
            #pragma unroll
            for (int r = 0; r < 4; ++r) {
                float4 a = *(const float4*)&sA[tr * 4 + r][kq * 4];
                float av[4] = {a.x, a.y, a.z, a.w};
                #pragma unroll
                for (int j = 0; j < 4; ++j)
                    #pragma unroll
                    for (int c = 0; c < 4; ++c)
                        acc[r][c] = fmaf(av[j], wj[j][c], acc[r][c]);
            }
        }
        __syncthreads();
    }
    float4 bb = *(const float4*)&bias[tc * 4];
    float bv[4] = {bb.x, bb.y, bb.z, bb.w};
    #pragma unroll
    for (int r = 0; r < 4; ++r) {
        int node = node0 + tr * 4 + r;
        float ex = exists[node];
        float4 o;
        o.x = fmaxf(acc[r][0] + bv[0], 0.f) * ex;
        o.y = fmaxf(acc[r][1] + bv[1], 0.f) * ex;
        o.z = fmaxf(acc[r][2] + bv[2], 0.f) * ex;
        o.w = fmaxf(acc[r][3] + bv[3], 0.f) * ex;
        *(float4*)(x + (size_t)node * 256 + tc * 4) = o;
    }
}

// ---------------- W -> transposed padded bf16 ----------------
__global__ __launch_bounds__(256) void prep_w_kernel(
    const float* __restrict__ W0, const float* __restrict__ W1,
    unsigned short* __restrict__ Wtb)
{
    int b = blockIdx.x;
    int layer = b >> 8, n = b & 255;
    const float* W = layer ? W1 : W0;
    unsigned short* dst = Wtb + (size_t)layer * 256 * KP + (size_t)n * KP;
    for (int k = threadIdx.x; k < KP; k += 256) {
        float v = (k < DNE) ? W[(size_t)k * 256 + n] : 0.0f;
        dst[k] = f2bf(v);
    }
}

// ---------------- counting sort of edges by src ----------------
__global__ __launch_bounds__(256) void count_int_kernel(
    const int* __restrict__ eidx, int* __restrict__ icnt)
{
    int t = blockIdx.x * 256 + threadIdx.x;
    if (t < NE) atomicAdd(&icnt[eidx[2 * t]], 1);
}

__global__ __launch_bounds__(256) void scan1_kernel(
    const int* __restrict__ icnt, int* __restrict__ part)
{
    __shared__ int sd[256];
    int i = blockIdx.x * 256 + threadIdx.x;
    sd[threadIdx.x] = (i < NC) ? icnt[i] : 0;
    __syncthreads();
    for (int d = 128; d > 0; d >>= 1) {
        if (threadIdx.x < d) sd[threadIdx.x] += sd[threadIdx.x + d];
        __syncthreads();
    }
    if (threadIdx.x == 0) part[blockIdx.x] = sd[0];
}

__global__ void scan2_kernel(int* __restrict__ part)
{
    if (threadIdx.x == 0) {
        int acc = 0;
        for (int i = 0; i < NB_SCAN; ++i) { int v = part[i]; part[i] = acc; acc += v; }
    }
}

__global__ __launch_bounds__(256) void scan3_kernel(
    const int* __restrict__ icnt, const int* __restrict__ part,
    int* __restrict__ cur)
{
    __shared__ int sc[256];
    const int t = threadIdx.x;
    int i = blockIdx.x * 256 + t;
    int val = (i < NC) ? icnt[i] : 0;
    sc[t] = val;
    __syncthreads();
    for (int d = 1; d < 256; d <<= 1) {
        int x = (t >= d) ? sc[t - d] : 0;
        __syncthreads();
        sc[t] += x;
        __syncthreads();
    }
    if (i < NC) cur[i] = part[blockIdx.x] + sc[t] - val;
}

__global__ __launch_bounds__(256) void bin_kernel(
    const int* __restrict__ eidx, int* __restrict__ cur, int* __restrict__ perm)
{
    int t = blockIdx.x * 256 + threadIdx.x;
    if (t < NE) {
        int s = eidx[2 * t];
        int p = atomicAdd(&cur[s], 1);
        perm[p] = t;
    }
}

__global__ __launch_bounds__(256) void inv_kernel(
    const int* __restrict__ icnt, float* __restrict__ inv)
{
    int t = blockIdx.x * 256 + threadIdx.x;
    if (t < NC) inv[t] = 1.0f / fmaxf((float)icnt[t], 1.0f);
}

// ---------------- fused edge layer (bf16 MFMA, src-sorted, segmented epilogue) ----------------
__global__ __launch_bounds__(256) void edge_mfma_kernel(
    const unsigned short* __restrict__ xb,
    const float* __restrict__ eto, const float* __restrict__ efe,
    const int* __restrict__ eidx, const int* __restrict__ perm,
    const unsigned short* __restrict__ Wtb,
    const float* __restrict__ bias,
    float* __restrict__ accb)
{
    __shared__ unsigned short sA[64][40];
    __shared__ unsigned short sB[256][40];
    __shared__ int s_src[64], s_dst[64], s_perm[64];
    __shared__ float ep[16][258];

    const int tid = threadIdx.x;
    const int e0 = blockIdx.x * 64;
    if (tid < 64) {
        int ee = e0 + tid; if (ee >= NE) ee = NE - 1;
        int e = perm[ee];
        s_perm[tid] = e;
        s_src[tid] = eidx[2 * e];
        s_dst[tid] = eidx[2 * e + 1];
    }
    const int lane = tid & 63;
    const int wid  = tid >> 6;
    const int wm   = wid >> 1;
    const int wn   = wid & 1;
    const int l15  = lane & 15;
    const int l4   = lane >> 4;

    const int arow = tid >> 2;
    const int acol = (tid & 3) * 8;

    f32x4 acc[2][8];
    #pragma unroll
    for (int mi = 0; mi < 2; ++mi)
        #pragma unroll
        for (int ni = 0; ni < 8; ++ni)
            acc[mi][ni] = (f32x4){0.f, 0.f, 0.f, 0.f};

    __syncthreads();

    for (int ch = 0; ch < 19; ++ch) {
        const int k0 = ch * 32;
        if (ch < 8) {
            int4 v = *(const int4*)(xb + (size_t)s_src[arow] * 256 + k0 + acol);
            *(int4*)&sA[arow][acol] = v;
        } else if (ch < 16) {
            int4 v = *(const int4*)(xb + (size_t)s_dst[arow] * 256 + (k0 - 256) + acol);
            *(int4*)&sA[arow][acol] = v;
        } else {
            int e = s_perm[arow];
            int gk = k0 + acol - 512;
            union { unsigned short u[8]; int4 v; } pk;
            #pragma unroll
            for (int j = 0; j < 8; ++j) {
                int g = gk + j;
                float f = 0.0f;
                if (g < 4)       f = eto[(size_t)e * 4 + g];
                else if (g < 68) f = efe[(size_t)e * 64 + (g - 4)];
                pk.u[j] = f2bf(f);
            }
            *(int4*)&sA[arow][acol] = pk.v;
        }
        #pragma unroll
        for (int i = 0; i < 4; ++i) {
            int s = tid + i * 256;
            int n = s >> 2, c8 = (s & 3) * 8;
            int4 v = *(const int4*)(Wtb + (size_t)n * KP + k0 + c8);
            *(int4*)&sB[n][c8] = v;
        }
        __syncthreads();
        bf16x8 af[2];
        #pragma unroll
        for (int mi = 0; mi < 2; ++mi)
            af[mi] = *(const bf16x8*)&sA[wm * 32 + mi * 16 + l15][l4 * 8];
        #pragma unroll
        for (int ni = 0; ni < 8; ++ni) {
            bf16x8 bfr = *(const bf16x8*)&sB[wn * 128 + ni * 16 + l15][l4 * 8];
            acc[0][ni] = __builtin_amdgcn_mfma_f32_16x16x32_bf16(af[0], bfr, acc[0][ni], 0, 0, 0);
            acc[1][ni] = __builtin_amdgcn_mfma_f32_16x16x32_bf16(af[1], bfr, acc[1][ni], 0, 0, 0);
        }
        __syncthreads();
    }

    // ---- segmented epilogue: relu(acc+bias), per-column run accumulation over sorted src ----
    float bv[8];
    #pragma unroll
    for (int ni = 0; ni < 8; ++ni)
        bv[ni] = bias[wn * 128 + ni * 16 + l15];

    const int col = tid;
    int curn = s_src[0];
    float run = 0.f;
    for (int c = 0; c < 4; ++c) {
        if (wm == (c >> 1)) {
            const int mi = c & 1;
            #pragma unroll
            for (int ni = 0; ni < 8; ++ni) {
                #pragma unroll
                for (int r = 0; r < 4; ++r) {
                    float v = fmaxf(acc[mi][ni][r] + bv[ni], 0.f);
                    ep[l4 * 4 + r][wn * 128 + ni * 16 + l15] = v;
                }
            }
        }
        __syncthreads();
        #pragma unroll
        for (int r = 0; r < 16; ++r) {
            int row = c * 16 + r;
            float v = ((e0 + row) < NE) ? ep[r][col] : 0.f;
            int sr = s_src[row];
            if (sr != curn) {
                atomicAdd(&accb[(size_t)curn * 256 + col], run);
                curn = sr; run = v;
            } else {
                run += v;
            }
        }
        __syncthreads();
    }
    atomicAdd(&accb[(size_t)curn * 256 + col], run);
}

// ---------------- per-node scale + bf16 convert + column max ----------------
__global__ __launch_bounds__(256) void finalize_kernel(
    const float* __restrict__ src, const float* __restrict__ inv,
    unsigned short* __restrict__ xb_out, float* __restrict__ pmax, int n)
{
    const int tid = threadIdx.x;
    int i0 = blockIdx.x * 128;
    int iend = i0 + 128; if (iend > n) iend = n;
    float m = 0.0f;
    for (int i = i0; i < iend; ++i) {
        float v = src[(size_t)i * 256 + tid];
        if (inv) v *= inv[i];
        xb_out[(size_t)i * 256 + tid] = f2bf(v);
        m = fmaxf(m, v);
    }
    atomicMax((unsigned int*)&pmax[tid], __float_as_uint(m));  // all v >= 0
}

__global__ __launch_bounds__(256) void parent_kernel(
    const float* __restrict__ pmax, const float* __restrict__ W,
    const float* __restrict__ bias, float* __restrict__ out)
{
    __shared__ float sp[768];
    const int tid = threadIdx.x;
    for (int i = tid; i < 768; i += 256) sp[i] = pmax[i];
    __syncthreads();
    float s = bias[tid];
    for (int k = 0; k < 768; ++k) s = fmaf(sp[k], W[(size_t)k * 256 + tid], s);
    out[tid] = fmaxf(s, 0.f);
}

extern "C" void kernel_launch(void* const* d_in, const int* in_sizes, int n_in,
                              void* d_out, int out_size, void* d_ws, size_t ws_size,
                              hipStream_t stream)
{
    const float* cf   = (const float*)d_in[0];
    const float* ex   = (const float*)d_in[1];
    const float* eto  = (const float*)d_in[2];
    const float* efe  = (const float*)d_in[3];
    const int*   eidx = (const int*)d_in[4];
    const float* Wc   = (const float*)d_in[5];
    const float* bc   = (const float*)d_in[6];
    const float* W0   = (const float*)d_in[7];
    const float* b0   = (const float*)d_in[8];
    const float* W1   = (const float*)d_in[9];
    const float* b1   = (const float*)d_in[10];
    const float* Wp   = (const float*)d_in[11];
    const float* bp   = (const float*)d_in[12];

    // workspace layout
    float*          accb = (float*)d_ws;                          // NC*256 f32 (also child tmp)
    float*          invv = accb + (size_t)NC * 256;               // NC f32
    float*          pmax = invv + NC;                             // 768 f32
    unsigned short* xb   = (unsigned short*)(pmax + 768);         // NC*256 bf16
    unsigned short* Wtb  = xb + (size_t)NC * 256;                 // 2*256*KP bf16
    int*            icnt = (int*)(Wtb + 2 * 256 * KP);            // NC
    int*            part = icnt + NC;                             // 256
    int*            curb = part + 256;                            // NC
    int*            perm = curb + NC;                             // NE

    hipMemsetAsync(pmax, 0, 768 * sizeof(float), stream);
    hipMemsetAsync(icnt, 0, NC * sizeof(int), stream);

    prep_w_kernel<<<512, 256, 0, stream>>>(W0, W1, Wtb);
    child_kernel<<<NC / 16, 256, 0, stream>>>(cf, ex, Wc, bc, accb);

    count_int_kernel<<<(NE + 255) / 256, 256, 0, stream>>>(eidx, icnt);
    scan1_kernel<<<NB_SCAN, 256, 0, stream>>>(icnt, part);
    scan2_kernel<<<1, 64, 0, stream>>>(part);
    scan3_kernel<<<NB_SCAN, 256, 0, stream>>>(icnt, part, curb);
    bin_kernel<<<(NE + 255) / 256, 256, 0, stream>>>(eidx, curb, perm);
    inv_kernel<<<(NC + 255) / 256, 256, 0, stream>>>(icnt, invv);

    finalize_kernel<<<(NC + 127) / 128, 256, 0, stream>>>(accb, nullptr, xb, pmax, NC);

    for (int it = 0; it < 2; ++it) {
        const unsigned short* Wt = Wtb + (size_t)it * 256 * KP;
        const float* b = it ? b1 : b0;
        hipMemsetAsync(accb, 0, (size_t)NC * 256 * sizeof(float), stream);
        edge_mfma_kernel<<<(NE + 63) / 64, 256, 0, stream>>>(xb, eto, efe, eidx, perm, Wt, b, accb);
        finalize_kernel<<<(NC + 127) / 128, 256, 0, stream>>>(accb, invv, xb, pmax + 256 * (it + 1), NC);
    }
    parent_kernel<<<1, 256, 0, stream>>>(pmax, Wp, bp, (float*)d_out);
}

// Round 4
// 830.111 us; speedup vs baseline: 6.5901x; 1.4221x over previous
//
#include <hip/hip_runtime.h>

#define NC   50000
#define NE   500000
#define DIN  313
#define DNE  580
#define KP   608          // padded K for edge GEMM (19*32)
#define KPC  320          // padded K for child GEMM (10*32)
#define NB_SCAN 196       // ceil(NC/256)

typedef __attribute__((ext_vector_type(8))) short bf16x8;
typedef __attribute__((ext_vector_type(4))) float f32x4;

static __device__ __forceinline__ unsigned short f2bf(float f) {
    unsigned u = __float_as_uint(f);
    unsigned r = (u + 0x7fff + ((u >> 16) & 1)) >> 16;   // RNE
    return (unsigned short)r;
}

static __device__ __forceinline__ void gload_lds16(const unsigned short* g, unsigned short* l) {
    __builtin_amdgcn_global_load_lds(
        (const __attribute__((address_space(1))) unsigned int*)(g),
        (__attribute__((address_space(3))) unsigned int*)(l), 16, 0, 0);
}

// ---------------- W prep: bf16, transposed, K-padded, chunk-PERMUTED so that a linear
// global_load_lds write leaves LDS slot s holding logical chunk s^(n&3) (XOR swizzle). ----------------
__global__ __launch_bounds__(256) void prep_w_kernel(
    const float* __restrict__ W0, const float* __restrict__ W1,
    const float* __restrict__ Wc,
    unsigned short* __restrict__ Wtb, unsigned short* __restrict__ Wct)
{
    int b = blockIdx.x;                 // 0..767
    int n = b & 255, which = b >> 8;
    const float* W; unsigned short* dst; int K, KPx;
    if (which < 2) { W = which ? W1 : W0; dst = Wtb + (size_t)which * 256 * KP + (size_t)n * KP; K = DNE; KPx = KP; }
    else           { W = Wc;              dst = Wct + (size_t)n * KPC;                            K = DIN; KPx = KPC; }
    for (int t = threadIdx.x; t < KPx; t += 256) {
        int ch = t >> 5, s = (t >> 3) & 3, j = t & 7;
        int gk = ch * 32 + ((s ^ (n & 3)) * 8) + j;    // pre-permute for swizzled LDS
        float v = (gk < K) ? W[(size_t)gk * 256 + n] : 0.0f;
        dst[t] = f2bf(v);
    }
}

// ---------------- child encoder (bf16 MFMA): xb = bf16(relu(cf@Wc+bc)*exists), pmax[0:256] ----------------
__global__ __launch_bounds__(256, 4) void child_mfma_kernel(
    const float* __restrict__ cf, const float* __restrict__ exists,
    const unsigned short* __restrict__ Wct, const float* __restrict__ bias,
    unsigned short* __restrict__ xb, float* __restrict__ pmax)
{
    __shared__ unsigned short sA[64][40];   // padded, unswizzled
    __shared__ unsigned short sB[256][32];  // linear, gload_lds, swizzled via prep
    __shared__ float smax[256];

    const int tid = threadIdx.x, lane = tid & 63, wid = tid >> 6;
    const int wm = wid >> 1, wn = wid & 1, l15 = lane & 15, l4 = lane >> 4;
    const int node0 = blockIdx.x * 64;
    const int arow = tid >> 2, s3 = tid & 3;

    smax[tid] = 0.0f;

    f32x4 acc[2][8];
    #pragma unroll
    for (int mi = 0; mi < 2; ++mi)
        #pragma unroll
        for (int ni = 0; ni < 8; ++ni)
            acc[mi][ni] = (f32x4){0.f, 0.f, 0.f, 0.f};

    int nodeA = node0 + arow; if (nodeA >= NC) nodeA = NC - 1;

    for (int ch = 0; ch < 10; ++ch) {
        // B: 4 gload_lds per thread (wave-uniform dest)
        #pragma unroll
        for (int i = 0; i < 4; ++i) {
            int n = (wid << 6) + (i << 4) + (lane >> 2);
            gload_lds16(Wct + (size_t)n * KPC + ch * 32 + (lane & 3) * 8,
                        &sB[(wid << 6) + (i << 4)][0]);
        }
        // A: 8 fp32 loads -> bf16 pack -> ds_write (padded, no swizzle)
        {
            int gk0 = ch * 32 + s3 * 8;
            union { unsigned short u[8]; int4 v; } pk;
            #pragma unroll
            for (int j = 0; j < 8; ++j) {
                int gk = gk0 + j;
                float f = (gk < DIN) ? cf[(size_t)nodeA * DIN + gk] : 0.0f;
                pk.u[j] = f2bf(f);
            }
            *(int4*)&sA[arow][s3 * 8] = pk.v;
        }
        __syncthreads();
        bf16x8 af[2];
        #pragma unroll
        for (int mi = 0; mi < 2; ++mi)
            af[mi] = *(const bf16x8*)&sA[wm * 32 + mi * 16 + l15][l4 * 8];
        #pragma unroll
        for (int ni = 0; ni < 8; ++ni) {
            int n = wn * 128 + ni * 16 + l15;
            bf16x8 bfr = *(const bf16x8*)&sB[n][(l4 ^ (n & 3)) * 8];
            acc[0][ni] = __builtin_amdgcn_mfma_f32_16x16x32_bf16(af[0], bfr, acc[0][ni], 0, 0, 0);
            acc[1][ni] = __builtin_amdgcn_mfma_f32_16x16x32_bf16(af[1], bfr, acc[1][ni], 0, 0, 0);
        }
        __syncthreads();
    }

    // fused epilogue: relu(+bias)*exists -> xb bf16 + column max
    float bv[8];
    #pragma unroll
    for (int ni = 0; ni < 8; ++ni) bv[ni] = bias[wn * 128 + ni * 16 + l15];
    float cmax[8];
    #pragma unroll
    for (int ni = 0; ni < 8; ++ni) cmax[ni] = 0.0f;

    #pragma unroll
    for (int mi = 0; mi < 2; ++mi) {
        #pragma unroll
        for (int r = 0; r < 4; ++r) {
            int node = node0 + wm * 32 + mi * 16 + l4 * 4 + r;
            if (node < NC) {
                float ex = exists[node];
                #pragma unroll
                for (int ni = 0; ni < 8; ++ni) {
                    float v = fmaxf(acc[mi][ni][r] + bv[ni], 0.f) * ex;
                    xb[(size_t)node * 256 + wn * 128 + ni * 16 + l15] = f2bf(v);
                    cmax[ni] = fmaxf(cmax[ni], v);
                }
            }
        }
    }
    #pragma unroll
    for (int ni = 0; ni < 8; ++ni)
        atomicMax((unsigned int*)&smax[wn * 128 + ni * 16 + l15], __float_as_uint(cmax[ni]));
    __syncthreads();
    atomicMax((unsigned int*)&pmax[tid], __float_as_uint(smax[tid]));
}

// ---------------- counting sort of edges by src ----------------
__global__ __launch_bounds__(256) void count_int_kernel(
    const int* __restrict__ eidx, int* __restrict__ icnt)
{
    int t = blockIdx.x * 256 + threadIdx.x;
    if (t < NE) atomicAdd(&icnt[eidx[2 * t]], 1);
}

__global__ __launch_bounds__(256) void scan1_kernel(
    const int* __restrict__ icnt, int* __restrict__ part)
{
    __shared__ int sd[256];
    int i = blockIdx.x * 256 + threadIdx.x;
    sd[threadIdx.x] = (i < NC) ? icnt[i] : 0;
    __syncthreads();
    for (int d = 128; d > 0; d >>= 1) {
        if (threadIdx.x < d) sd[threadIdx.x] += sd[threadIdx.x + d];
        __syncthreads();
    }
    if (threadIdx.x == 0) part[blockIdx.x] = sd[0];
}

__global__ void scan2_kernel(int* __restrict__ part)
{
    if (threadIdx.x == 0) {
        int acc = 0;
        for (int i = 0; i < NB_SCAN; ++i) { int v = part[i]; part[i] = acc; acc += v; }
    }
}

__global__ __launch_bounds__(256) void scan3_kernel(
    const int* __restrict__ icnt, const int* __restrict__ part,
    int* __restrict__ cur)
{
    __shared__ int sc[256];
    const int t = threadIdx.x;
    int i = blockIdx.x * 256 + t;
    int val = (i < NC) ? icnt[i] : 0;
    sc[t] = val;
    __syncthreads();
    for (int d = 1; d < 256; d <<= 1) {
        int x = (t >= d) ? sc[t - d] : 0;
        __syncthreads();
        sc[t] += x;
        __syncthreads();
    }
    if (i < NC) cur[i] = part[blockIdx.x] + sc[t] - val;
}

__global__ __launch_bounds__(256) void bin_kernel(
    const int* __restrict__ eidx, int* __restrict__ cur, int* __restrict__ perm)
{
    int t = blockIdx.x * 256 + threadIdx.x;
    if (t < NE) {
        int s = eidx[2 * t];
        int p = atomicAdd(&cur[s], 1);
        perm[p] = t;
    }
}

__global__ __launch_bounds__(256) void inv_kernel(
    const int* __restrict__ icnt, float* __restrict__ inv)
{
    int t = blockIdx.x * 256 + threadIdx.x;
    if (t < NC) inv[t] = 1.0f / fmaxf((float)icnt[t], 1.0f);
}

// ---------------- fused edge layer: 2-phase pipelined bf16 MFMA + segmented scatter ----------------
__global__ __launch_bounds__(256, 3) void edge_mfma_kernel(
    const unsigned short* __restrict__ xb,
    const float* __restrict__ eto, const float* __restrict__ efe,
    const int* __restrict__ eidx, const int* __restrict__ perm,
    const unsigned short* __restrict__ Wt,   // pre-permuted [256][KP]
    const float* __restrict__ bias,
    float* __restrict__ accb)
{
    __shared__ unsigned short sA[2][64][40];   // padded, unswizzled (reg-staged)
    __shared__ unsigned short sB[2][256][32];  // linear, gload_lds, swizzle baked into Wt
    __shared__ int s_src[64], s_dst[64], s_perm[64];

    const int tid = threadIdx.x;
    const int e0 = blockIdx.x * 64;
    if (tid < 64) {
        int ee = e0 + tid; if (ee >= NE) ee = NE - 1;
        int e = perm[ee];
        s_perm[tid] = e;
        s_src[tid] = eidx[2 * e];
        s_dst[tid] = eidx[2 * e + 1];
    }
    const int lane = tid & 63;
    const int wid  = tid >> 6;
    const int wm   = wid >> 1;
    const int wn   = wid & 1;
    const int l15  = lane & 15;
    const int l4   = lane >> 4;
    const int arow = tid >> 2;
    const int s3   = tid & 3;

    f32x4 acc[2][8];
    #pragma unroll
    for (int mi = 0; mi < 2; ++mi)
        #pragma unroll
        for (int ni = 0; ni < 8; ++ni)
            acc[mi][ni] = (f32x4){0.f, 0.f, 0.f, 0.f};

    __syncthreads();
    const int my_src = s_src[arow];
    const int my_dst = s_dst[arow];
    const int my_e   = s_perm[arow];

    // ---- prologue: stage chunk 0 into buf 0 ----
    #pragma unroll
    for (int i = 0; i < 4; ++i) {
        int n = (wid << 6) + (i << 4) + (lane >> 2);
        gload_lds16(Wt + (size_t)n * KP + (lane & 3) * 8, &sB[0][(wid << 6) + (i << 4)][0]);
    }
    {
        int4 av = *(const int4*)(xb + (size_t)my_src * 256 + s3 * 8);
        *(int4*)&sA[0][arow][s3 * 8] = av;
    }
    __syncthreads();

    int buf = 0;
    for (int ch = 0; ch < 19; ++ch) {
        const int nch = ch + 1;
        const bool do_stage = (nch < 19);
        int4 areg;
        float efr[8];
        // ---- STAGE issue for chunk nch into buf^1 ----
        if (do_stage) {
            #pragma unroll
            for (int i = 0; i < 4; ++i) {
                int n = (wid << 6) + (i << 4) + (lane >> 2);
                gload_lds16(Wt + (size_t)n * KP + nch * 32 + (lane & 3) * 8,
                            &sB[buf ^ 1][(wid << 6) + (i << 4)][0]);
            }
            if (nch < 8) {
                areg = *(const int4*)(xb + (size_t)my_src * 256 + nch * 32 + s3 * 8);
            } else if (nch < 16) {
                areg = *(const int4*)(xb + (size_t)my_dst * 256 + (nch * 32 - 256) + s3 * 8);
            } else {
                int gk0 = nch * 32 + s3 * 8 - 512;
                #pragma unroll
                for (int j = 0; j < 8; ++j) {
                    int g = gk0 + j;
                    float f = 0.0f;
                    if (g < 4)       f = eto[(size_t)my_e * 4 + g];
                    else if (g < 68) f = efe[(size_t)my_e * 64 + (g - 4)];
                    efr[j] = f;
                }
            }
        }
        // ---- compute chunk ch from buf ----
        bf16x8 af[2];
        #pragma unroll
        for (int mi = 0; mi < 2; ++mi)
            af[mi] = *(const bf16x8*)&sA[buf][wm * 32 + mi * 16 + l15][l4 * 8];
        #pragma unroll
        for (int ni = 0; ni < 8; ++ni) {
            int n = wn * 128 + ni * 16 + l15;
            bf16x8 bfr = *(const bf16x8*)&sB[buf][n][(l4 ^ (n & 3)) * 8];
            acc[0][ni] = __builtin_amdgcn_mfma_f32_16x16x32_bf16(af[0], bfr, acc[0][ni], 0, 0, 0);
            acc[1][ni] = __builtin_amdgcn_mfma_f32_16x16x32_bf16(af[1], bfr, acc[1][ni], 0, 0, 0);
        }
        // ---- write A for nch (late) ----
        if (do_stage) {
            if (nch < 16) {
                *(int4*)&sA[buf ^ 1][arow][s3 * 8] = areg;
            } else {
                union { unsigned short u[8]; int4 v; } pk;
                #pragma unroll
                for (int j = 0; j < 8; ++j) pk.u[j] = f2bf(efr[j]);
                *(int4*)&sA[buf ^ 1][arow][s3 * 8] = pk.v;
            }
        }
        __syncthreads();
        buf ^= 1;
    }

    // ---- segmented epilogue (ep overlays sB; stride 258 -> 2-way only) ----
    float (*ep)[258] = (float (*)[258])(&sB[0][0][0]);   // 16*258*4 = 16.5KB < 32KB

    float bv[8];
    #pragma unroll
    for (int ni = 0; ni < 8; ++ni)
        bv[ni] = bias[wn * 128 + ni * 16 + l15];

    const int col = tid;
    int curn = s_src[0];
    float run = 0.f;
    for (int c = 0; c < 4; ++c) {
        if (wm == (c >> 1)) {
            const int mi = c & 1;
            #pragma unroll
            for (int ni = 0; ni < 8; ++ni) {
                #pragma unroll
                for (int r = 0; r < 4; ++r) {
                    float v = fmaxf(acc[mi][ni][r] + bv[ni], 0.f);
                    ep[l4 * 4 + r][wn * 128 + ni * 16 + l15] = v;
                }
            }
        }
        __syncthreads();
        #pragma unroll
        for (int r = 0; r < 16; ++r) {
            int row = c * 16 + r;
            float v = ((e0 + row) < NE) ? ep[r][col] : 0.f;
            int sr = s_src[row];
            if (sr != curn) {
                atomicAdd(&accb[(size_t)curn * 256 + col], run);
                curn = sr; run = v;
            } else {
                run += v;
            }
        }
        __syncthreads();
    }
    atomicAdd(&accb[(size_t)curn * 256 + col], run);
}

// ---------------- per-node scale + bf16 convert + column max ----------------
__global__ __launch_bounds__(256) void finalize_kernel(
    const float* __restrict__ src, const float* __restrict__ inv,
    unsigned short* __restrict__ xb_out, float* __restrict__ pmax, int n)
{
    const int tid = threadIdx.x;
    int i0 = blockIdx.x * 128;
    int iend = i0 + 128; if (iend > n) iend = n;
    float m = 0.0f;
    for (int i = i0; i < iend; ++i) {
        float v = src[(size_t)i * 256 + tid];
        v *= inv[i];
        xb_out[(size_t)i * 256 + tid] = f2bf(v);
        m = fmaxf(m, v);
    }
    atomicMax((unsigned int*)&pmax[tid], __float_as_uint(m));  // all v >= 0
}

__global__ __launch_bounds__(256) void parent_kernel(
    const float* __restrict__ pmax, const float* __restrict__ W,
    const float* __restrict__ bias, float* __restrict__ out)
{
    __shared__ float sp[768];
    const int tid = threadIdx.x;
    for (int i = tid; i < 768; i += 256) sp[i] = pmax[i];
    __syncthreads();
    float s = bias[tid];
    for (int k = 0; k < 768; ++k) s = fmaf(sp[k], W[(size_t)k * 256 + tid], s);
    out[tid] = fmaxf(s, 0.f);
}

extern "C" void kernel_launch(void* const* d_in, const int* in_sizes, int n_in,
                              void* d_out, int out_size, void* d_ws, size_t ws_size,
                              hipStream_t stream)
{
    const float* cf   = (const float*)d_in[0];
    const float* ex   = (const float*)d_in[1];
    const float* eto  = (const float*)d_in[2];
    const float* efe  = (const float*)d_in[3];
    const int*   eidx = (const int*)d_in[4];
    const float* Wc   = (const float*)d_in[5];
    const float* bc   = (const float*)d_in[6];
    const float* W0   = (const float*)d_in[7];
    const float* b0   = (const float*)d_in[8];
    const float* W1   = (const float*)d_in[9];
    const float* b1   = (const float*)d_in[10];
    const float* Wp   = (const float*)d_in[11];
    const float* bp   = (const float*)d_in[12];

    // workspace layout
    float*          accb = (float*)d_ws;                          // NC*256 f32
    float*          invv = accb + (size_t)NC * 256;               // NC f32
    float*          pmax = invv + NC;                             // 768 f32
    unsigned short* xb   = (unsigned short*)(pmax + 768);         // NC*256 bf16
    unsigned short* Wtb  = xb + (size_t)NC * 256;                 // 2*256*KP bf16
    unsigned short* Wct  = Wtb + (size_t)2 * 256 * KP;            // 256*KPC bf16
    int*            icnt = (int*)(Wct + (size_t)256 * KPC);       // NC
    int*            part = icnt + NC;                             // 256
    int*            curb = part + 256;                            // NC
    int*            perm = curb + NC;                             // NE

    hipMemsetAsync(pmax, 0, 768 * sizeof(float), stream);
    hipMemsetAsync(icnt, 0, NC * sizeof(int), stream);

    prep_w_kernel<<<768, 256, 0, stream>>>(W0, W1, Wc, Wtb, Wct);
    child_mfma_kernel<<<(NC + 63) / 64, 256, 0, stream>>>(cf, ex, Wct, bc, xb, pmax);

    count_int_kernel<<<(NE + 255) / 256, 256, 0, stream>>>(eidx, icnt);
    scan1_kernel<<<NB_SCAN, 256, 0, stream>>>(icnt, part);
    scan2_kernel<<<1, 64, 0, stream>>>(part);
    scan3_kernel<<<NB_SCAN, 256, 0, stream>>>(icnt, part, curb);
    bin_kernel<<<(NE + 255) / 256, 256, 0, stream>>>(eidx, curb, perm);
    inv_kernel<<<(NC + 255) / 256, 256, 0, stream>>>(icnt, invv);

    for (int it = 0; it < 2; ++it) {
        const unsigned short* Wt = Wtb + (size_t)it * 256 * KP;
        const float* b = it ? b1 : b0;
        hipMemsetAsync(accb, 0, (size_t)NC * 256 * sizeof(float), stream);
        edge_mfma_kernel<<<(NE + 63) / 64, 256, 0, stream>>>(xb, eto, efe, eidx, perm, Wt, b, accb);
        finalize_kernel<<<(NC + 127) / 128, 256, 0, stream>>>(accb, invv, xb, pmax + 256 * (it + 1), NC);
    }
    parent_kernel<<<1, 256, 0, stream>>>(pmax, Wp, bp, (float*)d_out);
}